// Round 6
// baseline (16154.550 us; speedup 1.0000x reference)
//
#include <hip/hip_runtime.h>
#include <hip/hip_bf16.h>
#include <hip/hip_cooperative_groups.h>

namespace cg = cooperative_groups;

// Problem constants
#define B_  2048   // batch
#define T_  32     // T_SRC == T_TGT
#define D_  512    // model dim
#define G_  2048   // 4*D
#define VT_ 80     // D_TGT
#define BD  (B_ * D_)          // elems per state plane
#define LWE ((size_t)G_ * D_)  // per-layer weight elems

typedef _Float16 half8 __attribute__((ext_vector_type(8)));
typedef _Float16 half4_t __attribute__((ext_vector_type(4)));
typedef float    f32x4 __attribute__((ext_vector_type(4)));

#define MFMA16(a, b, c) __builtin_amdgcn_mfma_f32_16x16x32_f16(a, b, c, 0, 0, 0)

static __device__ __forceinline__ float sigm(float x) {
    return 1.0f / (1.0f + expf(-x));
}

// global -> LDS direct copy, 16B per lane (64 lanes = 1 KB per issue).
typedef __attribute__((address_space(1))) unsigned int gas_u32;
typedef __attribute__((address_space(3))) unsigned int las_u32;
static __device__ __forceinline__ void glds16(const void* src, void* dst) {
    __builtin_amdgcn_global_load_lds(
        (gas_u32*)(unsigned long long)(size_t)src,
        (las_u32*)(unsigned int)(size_t)dst, 16, 0, 0);
}

// ---------------------------------------------------------------------------
__global__ void zero_ws(int4* __restrict__ p, int n) {
    int i = blockIdx.x * blockDim.x + threadIdx.x;
    if (i < n) p[i] = int4{0, 0, 0, 0};
}
__global__ void init_pred(const int* __restrict__ tgt, int* __restrict__ pred) {
    int i = blockIdx.x * blockDim.x + threadIdx.x;
    if (i < B_) pred[i] = tgt[i * T_];
}

// ---------------------------------------------------------------------------
// Split 6 weight matrices (fp32 GxD) into fp16 hi/lo planes, gate-interleaved
// column order n' = d*4 + g, MFMA B-frag tile order:
// tile(NI=n'>>4, KC=k>>5), lane = (n'&15) | (((k>>3)&3)<<4), elem = k&7.
// ---------------------------------------------------------------------------
__global__ void split_weights(const float* __restrict__ s0, const float* __restrict__ s1,
                              const float* __restrict__ s2, const float* __restrict__ s3,
                              const float* __restrict__ s4, const float* __restrict__ s5,
                              _Float16* __restrict__ Wbase) {
    int g = blockIdx.x * blockDim.x + threadIdx.x;   // 6 * 2048 * 64
    int mat = g >> 17;
    int rem = g & 131071;
    int np  = rem >> 6;
    int kq  = rem & 63;                               // k-octet
    const float* src = (mat == 0) ? s0 : (mat == 1) ? s1 : (mat == 2) ? s2
                     : (mat == 3) ? s3 : (mat == 4) ? s4 : s5;
    int n = (np & 3) * D_ + (np >> 2);
    const float* sp = src + (size_t)n * D_ + kq * 8;
    float4 v0 = ((const float4*)sp)[0], v1 = ((const float4*)sp)[1];
    float x[8] = {v0.x, v0.y, v0.z, v0.w, v1.x, v1.y, v1.z, v1.w};
    _Float16 hi[8], lo[8];
    #pragma unroll
    for (int u = 0; u < 8; ++u) {
        hi[u] = (_Float16)x[u];
        lo[u] = (_Float16)(x[u] - (float)hi[u]);
    }
    int tile = (np >> 4) * 16 + (kq >> 2);
    int lane = (np & 15) | ((kq & 3) << 4);
    size_t e = (size_t)tile * 512 + (size_t)lane * 8;
    _Float16* Whi = Wbase + (size_t)mat * (2 * LWE);
    _Float16* Wlo = Whi + LWE;
    *(half8*)(Whi + e) = *(half8*)hi;
    *(half8*)(Wlo + e) = *(half8*)lo;
}

// ---------------------------------------------------------------------------
// post_W (80 x 512 fp32) -> hi/lo fp16 B-frag tiles, n' = v.
// ---------------------------------------------------------------------------
__global__ void split_postW(const float* __restrict__ pw,
                            _Float16* __restrict__ Ph, _Float16* __restrict__ Pl) {
    int g = blockIdx.x * blockDim.x + threadIdx.x;   // 80*64 = 5120
    if (g >= VT_ * 64) return;
    int v = g >> 6, kq = g & 63;
    const float* sp = pw + (size_t)v * D_ + kq * 8;
    float4 v0 = ((const float4*)sp)[0], v1 = ((const float4*)sp)[1];
    float x[8] = {v0.x, v0.y, v0.z, v0.w, v1.x, v1.y, v1.z, v1.w};
    _Float16 hi[8], lo[8];
    #pragma unroll
    for (int u = 0; u < 8; ++u) {
        hi[u] = (_Float16)x[u];
        lo[u] = (_Float16)(x[u] - (float)hi[u]);
    }
    int tile = (v >> 4) * 16 + (kq >> 2);
    int lane = (v & 15) | ((kq & 3) << 4);
    size_t e = (size_t)tile * 512 + (size_t)lane * 8;
    *(half8*)(Ph + e) = *(half8*)hi;
    *(half8*)(Pl + e) = *(half8*)lo;
}

// ---------------------------------------------------------------------------
__global__ void perm_bias(const float* __restrict__ ebih, const float* __restrict__ ebhh,
                          const float* __restrict__ dbih, const float* __restrict__ dbhh,
                          float* __restrict__ biasP) {
    int i = blockIdx.x * blockDim.x + threadIdx.x;   // 0..8191
    int cfg = i >> 11, np = i & 2047;
    int n = (np & 3) * D_ + (np >> 2);
    const float* bi = ((cfg < 2) ? ebih : dbih) + (cfg & 1) * G_;
    const float* bh = ((cfg < 2) ? ebhh : dbhh) + (cfg & 1) * G_;
    biasP[cfg * G_ + np] = bi[n] + bh[n];
}

// ---------------------------------------------------------------------------
// Exact fp32 input projections, permuted n'. 18 row-groups of 10 rows.
// ---------------------------------------------------------------------------
__global__ __launch_bounds__(256) void compute_P(
    const float* __restrict__ enc_emb, const float* __restrict__ dec_emb,
    const float* __restrict__ encW0,   const float* __restrict__ decW0,
    float* __restrict__ P) {
    __shared__ float es[10][D_];
    __shared__ float part[4][64][10];
    int by = blockIdx.y;
    bool enc = (by < 10);
    int r0 = enc ? by * 10 : 100 + (by - 10) * 10;
    int s0 = enc ? by * 10 : (by - 10) * 10;
    const float* emb = enc ? enc_emb : dec_emb;
    const float* W   = enc ? encW0 : decW0;
    int tid = threadIdx.x;
    #pragma unroll
    for (int it = 0; it < 5; ++it) {
        int i4 = it * 256 + tid;
        int rr = i4 >> 7, cc = i4 & 127;
        ((float4*)es[rr])[cc] = ((const float4*)(emb + (size_t)(s0 + rr) * D_))[cc];
    }
    __syncthreads();
    int o   = tid & 63;
    int seg = tid >> 6;
    int np = blockIdx.x * 64 + o;
    int n = (np & 3) * D_ + (np >> 2);
    const float* wr = W + (size_t)n * D_ + seg * 128;
    float acc[10];
    #pragma unroll
    for (int rr = 0; rr < 10; ++rr) acc[rr] = 0.f;
    for (int k = 0; k < 128; k += 4) {
        float4 w4 = *(const float4*)(wr + k);
        int kb = seg * 128 + k;
        #pragma unroll
        for (int rr = 0; rr < 10; ++rr)
            acc[rr] += es[rr][kb] * w4.x + es[rr][kb+1] * w4.y
                     + es[rr][kb+2] * w4.z + es[rr][kb+3] * w4.w;
    }
    #pragma unroll
    for (int rr = 0; rr < 10; ++rr) part[seg][o][rr] = acc[rr];
    __syncthreads();
    for (int i = tid; i < 640; i += 256) {
        int o2 = i & 63, rr = i >> 6;
        P[(size_t)(r0 + rr) * G_ + blockIdx.x * 64 + o2] =
            (part[0][o2][rr] + part[1][o2][rr]) + (part[2][o2][rr] + part[3][o2][rr]);
    }
}

// ---------------------------------------------------------------------------
// R13: persistent cooperative kernel. 256 blocks x 512 thr (1 block/CU).
// Group split by XCD: xcd = b%8; grp0 (xcd 0-3) runs layer-0 cells (+logits),
// grp1 (xcd 4-7) runs layer-1 cells. Each block permanently holds its
// group's weight slice (16 n' columns) in LDS: grp0 Whh (32 KB), grp1
// Wih+Whh (64 KB). Weights are staged ONCE per program phase (enc / dec).
// c-state lives in VGPRs for the whole run (thread owns (row,d) cells).
// h ping-pongs through global fp16 hi/lo frag-tile planes; grid.sync()
// provides cross-XCD visibility between phases.
//
// Per cell phase, per block: gates[all 2048 rows x its 16 n'] via MFMA,
// B-frags from LDS, A-frags streamed from the h planes (shared via L2 --
// all blocks sweep K in lockstep between grid syncs).
// ---------------------------------------------------------------------------
struct PersistArgs {
    const _Float16 *W0, *W1, *W2, *W3, *W4, *W5;   // hi base; lo at +LWE
    const _Float16 *PwH, *PwL;
    const float *biasB;
    const float *Ptab;
    const int *src;
    int *pred;
    const float *postb;
    float *out;
    _Float16 *Hh00, *Hl00, *Hh01, *Hl01;           // layer0 slots 0/1
    _Float16 *Hh10, *Hl10, *Hh11, *Hl11;           // layer1 slots 0/1
};

__global__ void __launch_bounds__(512, 1) lstm_persistent(PersistArgs A) {
    extern __shared__ char dsm[];    // 65536 weights + 8*1280 scratch = 75776
    cg::grid_group grid = cg::this_grid();

    const int b    = blockIdx.x;
    const int xcd  = b & 7;
    const int grp  = (xcd >= 4) ? 1 : 0;
    const int gi   = (b >> 3) * 4 + (xcd & 3);   // 0..127 within group
    const int tid  = threadIdx.x;
    const int wv   = tid >> 6;                   // 0..7
    const int lane = tid & 63;

    float* scr = (float*)(dsm + 65536 + wv * 1280);   // per-wave 16x20 f32

    // persistent cell state: thread owns rows m=(wv*16+f)*16+(lane>>2),
    // col d = gi*4 + (lane&3), f = 0..15.
    float cst[16];
    #pragma unroll
    for (int f = 0; f < 16; ++f) cst[f] = 0.f;

    // ---- weight staging: one mat (32 KB) into LDS slot 0/1 ----
    auto stageW = [&](const _Float16* Wbase, int slot) {
        const _Float16* Whi = Wbase;
        const _Float16* Wlo = Wbase + LWE;
        for (int j = wv; j < 32; j += 8) {           // (kc, plane) units
            int kc = j >> 1, pl = j & 1;
            const _Float16* s = (pl ? Wlo : Whi)
                              + (((size_t)(gi * 16 + kc)) << 9) + (size_t)lane * 8;
            glds16(s, dsm + slot * 32768 + kc * 2048 + pl * 1024);
        }
    };

    // ---- one LSTM cell pass over this block's n'-slice, all 2048 rows ----
    auto cell = [&](int nmat,
                    const _Float16* Axh, const _Float16* Axl,   // A for LDS slot0 mat
                    const _Float16* Arh, const _Float16* Arl,   // A for LDS slot1 mat
                    int cfg, const float* Prow,
                    const int* idx, int idxstride, int idxoff, int idxmax,
                    _Float16* Hho, _Float16* Hlo_) {
        f32x4 acc[16];
        #pragma unroll
        for (int f = 0; f < 16; ++f) acc[f] = f32x4{0.f, 0.f, 0.f, 0.f};
        const size_t lo8  = (size_t)lane * 8;
        const size_t lo16 = (size_t)lane * 16;
        const int mi0 = wv * 16;
        for (int kc = 0; kc < 16; ++kc) {
            const char* wb = dsm + kc * 2048 + lo16;
            half8 B0h = *(const half8*)(wb);
            half8 B0l = *(const half8*)(wb + 1024);
            half8 B1h = {}, B1l = {};
            if (nmat == 2) {
                B1h = *(const half8*)(wb + 32768);
                B1l = *(const half8*)(wb + 32768 + 1024);
            }
            #pragma unroll
            for (int f = 0; f < 16; ++f) {
                size_t off = (((size_t)((mi0 + f) * 16 + kc)) << 9) + lo8;
                half8 axh = *(const half8*)(Axh + off);
                half8 axl = *(const half8*)(Axl + off);
                acc[f] = MFMA16(axh, B0h, acc[f]);
                acc[f] = MFMA16(axh, B0l, acc[f]);
                acc[f] = MFMA16(axl, B0h, acc[f]);
                if (nmat == 2) {
                    half8 arh = *(const half8*)(Arh + off);
                    half8 arl = *(const half8*)(Arl + off);
                    acc[f] = MFMA16(arh, B1h, acc[f]);
                    acc[f] = MFMA16(arh, B1l, acc[f]);
                    acc[f] = MFMA16(arl, B1h, acc[f]);
                }
            }
        }
        // ---- epilogue: per-wave 16x16 transpose via LDS, LSTM math ----
        const int rr0  = (lane >> 4) << 2;
        const int ccol = lane & 15;
        const int row  = lane >> 2;
        const int dd   = lane & 3;
        const int d    = gi * 4 + dd;
        const float4 bvec = *(const float4*)(A.biasB + cfg * G_ + gi * 16 + dd * 4);
        const size_t hbase = (size_t)(row | (((d >> 3) & 3) << 4)) * 8 + (d & 7);
        #pragma unroll
        for (int f = 0; f < 16; ++f) {
            scr[(rr0 + 0) * 20 + ccol] = acc[f][0];
            scr[(rr0 + 1) * 20 + ccol] = acc[f][1];
            scr[(rr0 + 2) * 20 + ccol] = acc[f][2];
            scr[(rr0 + 3) * 20 + ccol] = acc[f][3];
            asm volatile("s_waitcnt lgkmcnt(0)" ::: "memory");
            float4 gv = *(const float4*)(scr + row * 20 + dd * 4);
            asm volatile("s_waitcnt lgkmcnt(0)" ::: "memory");
            float xi = gv.x + bvec.x, xf = gv.y + bvec.y;
            float xg = gv.z + bvec.z, xo = gv.w + bvec.w;
            if (Prow) {
                int m = (mi0 + f) * 16 + row;
                int s = idx[m * idxstride + idxoff];
                s = min(max(s, 0), idxmax - 1);
                const float4 pv = *(const float4*)(Prow + (size_t)s * G_ + gi * 16 + dd * 4);
                xi += pv.x; xf += pv.y; xg += pv.z; xo += pv.w;
            }
            float cn = sigm(xf) * cst[f] + sigm(xi) * tanhf(xg);
            float hn = sigm(xo) * tanhf(cn);
            cst[f] = cn;
            _Float16 hH = (_Float16)hn;
            _Float16 hL = (_Float16)(hn - (float)hH);
            size_t hoff = (((size_t)((mi0 + f) * 16 + (d >> 5))) << 9) + hbase;
            Hho[hoff]  = hH;
            Hlo_[hoff] = hL;
        }
    };

    // ---- logits + argmax for rows [gi*16, gi*16+16) (grp0 only) ----
    auto logits = [&](int t, const _Float16* H1h, const _Float16* H1l) {
        float* scr2 = (float*)(dsm + 65536);     // [16][88] f32
        float* pb   = scr2 + 16 * 88;            // 80 f32
        if (tid < VT_) pb[tid] = A.postb[tid];
        if (wv < 5) {
            const int j = wv;
            f32x4 acc = f32x4{0.f, 0.f, 0.f, 0.f};
            const size_t lo8 = (size_t)lane * 8;
            for (int kc = 0; kc < 16; ++kc) {
                size_t aoff = (((size_t)(gi * 16 + kc)) << 9) + lo8;
                half8 ah = *(const half8*)(H1h + aoff);
                half8 al = *(const half8*)(H1l + aoff);
                size_t boff = (((size_t)(j * 16 + kc)) << 9) + lo8;
                half8 bh = *(const half8*)(A.PwH + boff);
                half8 bl = *(const half8*)(A.PwL + boff);
                acc = MFMA16(ah, bh, acc);
                acc = MFMA16(ah, bl, acc);
                acc = MFMA16(al, bh, acc);
            }
            const int q = lane >> 4, c = lane & 15;
            #pragma unroll
            for (int r = 0; r < 4; ++r)
                scr2[(q * 4 + r) * 88 + j * 16 + c] = acc[r];
        }
        __syncthreads();
        if (tid < 16) {
            const int r = tid;
            float best = -3.4e38f; int bi = 0;
            #pragma unroll
            for (int v = 0; v < VT_; ++v) {
                float x = scr2[r * 88 + v] + pb[v];
                if (x > best) { best = x; bi = v; }
            }
            A.pred[gi * 16 + r] = bi;
            float* orow = A.out + (size_t)(gi * 16 + r) * (T_ * VT_) + (size_t)t * VT_;
            #pragma unroll
            for (int v4 = 0; v4 < VT_; v4 += 4) {
                float4 g4 = *(float4*)(scr2 + r * 88 + v4);
                float4 b4 = *(float4*)(pb + v4);
                *(float4*)(orow + v4) = float4{g4.x + b4.x, g4.y + b4.y,
                                               g4.z + b4.z, g4.w + b4.w};
            }
        }
        __syncthreads();
    };

    // ---- stage encoder weights ----
    if (grp == 0) stageW(A.W0, 0);
    else { stageW(A.W1, 0); stageW(A.W2, 1); }
    asm volatile("s_waitcnt vmcnt(0)" ::: "memory");
    __syncthreads();

    const _Float16 *h0hr = A.Hh00, *h0lr = A.Hl00;
    _Float16 *h0hw = A.Hh01, *h0lw = A.Hl01;
    const _Float16 *h1hr = A.Hh10, *h1lr = A.Hl10;
    _Float16 *h1hw = A.Hh11, *h1lw = A.Hl11;

#define SWAP0() { const _Float16* t1_ = h0hr; h0hr = h0hw; h0hw = (_Float16*)t1_; \
                  const _Float16* t2_ = h0lr; h0lr = h0lw; h0lw = (_Float16*)t2_; }
#define SWAP1() { const _Float16* t1_ = h1hr; h1hr = h1hw; h1hw = (_Float16*)t1_; \
                  const _Float16* t2_ = h1lr; h1lr = h1lw; h1lw = (_Float16*)t2_; }

    // -------- encoder: L1(t) on grp1  ||  L0(t+1) on grp0 --------
    if (grp == 0)
        cell(1, h0hr, h0lr, nullptr, nullptr, 0, A.Ptab, A.src, T_, 0, 100, h0hw, h0lw);
    grid.sync();
    SWAP0();
    for (int t = 0; t < T_ - 1; ++t) {
        if (grp == 1)
            cell(2, h0hr, h0lr, h1hr, h1lr, 1, nullptr, nullptr, 0, 0, 1, h1hw, h1lw);
        else
            cell(1, h0hr, h0lr, nullptr, nullptr, 0, A.Ptab, A.src, T_, t + 1, 100, h0hw, h0lw);
        grid.sync();
        SWAP0(); SWAP1();
    }
    if (grp == 1)
        cell(2, h0hr, h0lr, h1hr, h1lr, 1, nullptr, nullptr, 0, 0, 1, h1hw, h1lw);
    grid.sync();
    SWAP1();

    // ---- stage decoder weights (enc weights dead now) ----
    if (grp == 0) stageW(A.W3, 0);
    else { stageW(A.W4, 0); stageW(A.W5, 1); }
    asm volatile("s_waitcnt vmcnt(0)" ::: "memory");
    __syncthreads();

    // -------- decoder: serial L0 -> L1 -> logits per step --------
    const float* Pdec = A.Ptab + (size_t)100 * G_;
    for (int t = 0; t < T_; ++t) {
        if (grp == 0)
            cell(1, h0hr, h0lr, nullptr, nullptr, 2, Pdec, A.pred, 1, 0, VT_, h0hw, h0lw);
        grid.sync();
        SWAP0();
        if (grp == 1)
            cell(2, h0hr, h0lr, h1hr, h1lr, 3, nullptr, nullptr, 0, 0, 1, h1hw, h1lw);
        grid.sync();
        SWAP1();
        if (grp == 0) logits(t, h1hr, h1lr);
        grid.sync();
    }
#undef SWAP0
#undef SWAP1
}

// ---------------------------------------------------------------------------
extern "C" void kernel_launch(void* const* d_in, const int* in_sizes, int n_in,
                              void* d_out, int out_size, void* d_ws, size_t ws_size,
                              hipStream_t stream) {
    (void)in_sizes; (void)n_in; (void)out_size; (void)ws_size;

    const int*   src     = (const int*)d_in[0];
    const int*   tgt     = (const int*)d_in[1];
    const float* enc_emb = (const float*)d_in[2];
    const float* dec_emb = (const float*)d_in[3];
    const float* enc_Wih = (const float*)d_in[4];
    const float* enc_Whh = (const float*)d_in[5];
    const float* enc_bih = (const float*)d_in[6];
    const float* enc_bhh = (const float*)d_in[7];
    const float* dec_Wih = (const float*)d_in[8];
    const float* dec_Whh = (const float*)d_in[9];
    const float* dec_bih = (const float*)d_in[10];
    const float* dec_bhh = (const float*)d_in[11];
    const float* post_W  = (const float*)d_in[12];
    const float* post_b  = (const float*)d_in[13];

    // ---- ws layout (~50 MiB) ----
    char* wsb = (char*)d_ws;
    int*   pred  = (int*)wsb;                                   // 16 KB
    float* biasB = (float*)(wsb + 16384);                       // 32 KB
    float* Ptab  = (float*)(wsb + 16384 + 32768);               // 1.41 MiB
    char*  zbase = wsb + 16384 + 32768 + 180 * G_ * 4;          // zero-span
    float* C0 = (float*)zbase;                                  // (unused, zeroed)
    float* C1 = C0 + BD;
    _Float16* Hh00 = (_Float16*)(C1 + BD);
    _Float16* Hh10 = Hh00 + BD;
    _Float16* Hl00 = Hh10 + BD;
    _Float16* Hl10 = Hl00 + BD;
    _Float16* Hh01 = Hl10 + BD;   // not zeroed (fully written before read)
    _Float16* Hh11 = Hh01 + BD;
    _Float16* Hl01 = Hh11 + BD;
    _Float16* Hl11 = Hl01 + BD;
    _Float16* Wb   = Hl11 + BD;                      // 6 split matrices, 24 MiB
    _Float16* PwH  = Wb + 6 * 2 * LWE;               // post_W hi frag tiles
    _Float16* PwL  = PwH + (size_t)VT_ * D_;         // post_W lo frag tiles

    float* out = (float*)d_out;

    // ---- precompute ----
    zero_ws<<<4096, 256, 0, stream>>>((int4*)zbase, (16 * 1024 * 1024) / 16);
    init_pred<<<8, 256, 0, stream>>>(tgt, pred);
    split_weights<<<3072, 256, 0, stream>>>(
        enc_Whh, enc_Wih + LWE, enc_Whh + LWE,
        dec_Whh, dec_Wih + LWE, dec_Whh + LWE, Wb);
    split_postW<<<20, 256, 0, stream>>>(post_W, PwH, PwL);
    perm_bias<<<32, 256, 0, stream>>>(enc_bih, enc_bhh, dec_bih, dec_bhh, biasB);
    {
        dim3 gP(32, 18);
        compute_P<<<gP, 256, 0, stream>>>(enc_emb, dec_emb, enc_Wih, dec_Wih, Ptab);
    }

    // ---- persistent cooperative kernel ----
    static int s_attr = 0;
    if (!s_attr) {
        hipFuncSetAttribute((const void*)lstm_persistent,
                            hipFuncAttributeMaxDynamicSharedMemorySize, 75776);
        s_attr = 1;
    }
    PersistArgs pa;
    pa.W0 = Wb + (size_t)0 * (2 * LWE);
    pa.W1 = Wb + (size_t)1 * (2 * LWE);
    pa.W2 = Wb + (size_t)2 * (2 * LWE);
    pa.W3 = Wb + (size_t)3 * (2 * LWE);
    pa.W4 = Wb + (size_t)4 * (2 * LWE);
    pa.W5 = Wb + (size_t)5 * (2 * LWE);
    pa.PwH = PwH; pa.PwL = PwL;
    pa.biasB = biasB; pa.Ptab = Ptab;
    pa.src = src; pa.pred = pred;
    pa.postb = post_b; pa.out = out;
    pa.Hh00 = Hh00; pa.Hl00 = Hl00; pa.Hh01 = Hh01; pa.Hl01 = Hl01;
    pa.Hh10 = Hh10; pa.Hl10 = Hl10; pa.Hh11 = Hh11; pa.Hl11 = Hl11;
    void* kargs[] = { (void*)&pa };
    hipLaunchCooperativeKernel((const void*)lstm_persistent, dim3(256), dim3(512),
                               kargs, 75776, stream);
}

// Round 8
// 4471.421 us; speedup vs baseline: 3.6128x; 3.6128x over previous
//
#include <hip/hip_runtime.h>
#include <hip/hip_bf16.h>

// Problem constants
#define B_  2048   // batch
#define T_  32     // T_SRC == T_TGT
#define D_  512    // model dim
#define G_  2048   // 4*D
#define VT_ 80     // D_TGT
#define BD  (B_ * D_)          // elems per state plane
#define LWE ((size_t)G_ * D_)  // per-layer weight elems

typedef _Float16 half8 __attribute__((ext_vector_type(8)));
typedef _Float16 half4_t __attribute__((ext_vector_type(4)));
typedef float    f32x4 __attribute__((ext_vector_type(4)));

#define MFMA16(a, b, c) __builtin_amdgcn_mfma_f32_16x16x32_f16(a, b, c, 0, 0, 0)

static __device__ __forceinline__ float sigm(float x) {
    return 1.0f / (1.0f + expf(-x));
}

// global -> LDS direct copy, 16B per lane (64 lanes = 1 KB per issue).
typedef __attribute__((address_space(1))) unsigned int gas_u32;
typedef __attribute__((address_space(3))) unsigned int las_u32;
static __device__ __forceinline__ void glds16(const void* src, void* dst) {
    __builtin_amdgcn_global_load_lds(
        (gas_u32*)(unsigned long long)(size_t)src,
        (las_u32*)(unsigned int)(size_t)dst, 16, 0, 0);
}

// ---------------------------------------------------------------------------
__global__ void zero_ws(int4* __restrict__ p, int n) {
    int i = blockIdx.x * blockDim.x + threadIdx.x;
    if (i < n) p[i] = int4{0, 0, 0, 0};
}
__global__ void init_pred(const int* __restrict__ tgt, int* __restrict__ pred) {
    int i = blockIdx.x * blockDim.x + threadIdx.x;
    if (i < B_) pred[i] = tgt[i * T_];
}

// ---------------------------------------------------------------------------
// Split 6 weight matrices (fp32 GxD) into fp16 hi/lo planes, gate-interleaved
// column order n' = d*4 + g, MFMA B-frag tile order:
// tile(NI=n'>>4, KC=k>>5), lane = (n'&15) | (((k>>3)&3)<<4), elem = k&7.
// ---------------------------------------------------------------------------
__global__ void split_weights(const float* __restrict__ s0, const float* __restrict__ s1,
                              const float* __restrict__ s2, const float* __restrict__ s3,
                              const float* __restrict__ s4, const float* __restrict__ s5,
                              _Float16* __restrict__ Wbase) {
    int g = blockIdx.x * blockDim.x + threadIdx.x;   // 6 * 2048 * 64
    int mat = g >> 17;
    int rem = g & 131071;
    int np  = rem >> 6;
    int kq  = rem & 63;                               // k-octet
    const float* src = (mat == 0) ? s0 : (mat == 1) ? s1 : (mat == 2) ? s2
                     : (mat == 3) ? s3 : (mat == 4) ? s4 : s5;
    int n = (np & 3) * D_ + (np >> 2);
    const float* sp = src + (size_t)n * D_ + kq * 8;
    float4 v0 = ((const float4*)sp)[0], v1 = ((const float4*)sp)[1];
    float x[8] = {v0.x, v0.y, v0.z, v0.w, v1.x, v1.y, v1.z, v1.w};
    _Float16 hi[8], lo[8];
    #pragma unroll
    for (int u = 0; u < 8; ++u) {
        hi[u] = (_Float16)x[u];
        lo[u] = (_Float16)(x[u] - (float)hi[u]);
    }
    int tile = (np >> 4) * 16 + (kq >> 2);
    int lane = (np & 15) | ((kq & 3) << 4);
    size_t e = (size_t)tile * 512 + (size_t)lane * 8;
    _Float16* Whi = Wbase + (size_t)mat * (2 * LWE);
    _Float16* Wlo = Whi + LWE;
    *(half8*)(Whi + e) = *(half8*)hi;
    *(half8*)(Wlo + e) = *(half8*)lo;
}

// ---------------------------------------------------------------------------
// post_W (80 x 512 fp32) -> hi/lo fp16 B-frag tiles, n' = v.
// ---------------------------------------------------------------------------
__global__ void split_postW(const float* __restrict__ pw,
                            _Float16* __restrict__ Ph, _Float16* __restrict__ Pl) {
    int g = blockIdx.x * blockDim.x + threadIdx.x;   // 80*64 = 5120
    if (g >= VT_ * 64) return;
    int v = g >> 6, kq = g & 63;
    const float* sp = pw + (size_t)v * D_ + kq * 8;
    float4 v0 = ((const float4*)sp)[0], v1 = ((const float4*)sp)[1];
    float x[8] = {v0.x, v0.y, v0.z, v0.w, v1.x, v1.y, v1.z, v1.w};
    _Float16 hi[8], lo[8];
    #pragma unroll
    for (int u = 0; u < 8; ++u) {
        hi[u] = (_Float16)x[u];
        lo[u] = (_Float16)(x[u] - (float)hi[u]);
    }
    int tile = (v >> 4) * 16 + (kq >> 2);
    int lane = (v & 15) | ((kq & 3) << 4);
    size_t e = (size_t)tile * 512 + (size_t)lane * 8;
    *(half8*)(Ph + e) = *(half8*)hi;
    *(half8*)(Pl + e) = *(half8*)lo;
}

// ---------------------------------------------------------------------------
__global__ void perm_bias(const float* __restrict__ ebih, const float* __restrict__ ebhh,
                          const float* __restrict__ dbih, const float* __restrict__ dbhh,
                          float* __restrict__ biasP) {
    int i = blockIdx.x * blockDim.x + threadIdx.x;   // 0..8191
    int cfg = i >> 11, np = i & 2047;
    int n = (np & 3) * D_ + (np >> 2);
    const float* bi = ((cfg < 2) ? ebih : dbih) + (cfg & 1) * G_;
    const float* bh = ((cfg < 2) ? ebhh : dbhh) + (cfg & 1) * G_;
    biasP[cfg * G_ + np] = bi[n] + bh[n];
}

// ---------------------------------------------------------------------------
// Exact fp32 input projections, permuted n'. 18 row-groups of 10 rows.
// ---------------------------------------------------------------------------
__global__ __launch_bounds__(256) void compute_P(
    const float* __restrict__ enc_emb, const float* __restrict__ dec_emb,
    const float* __restrict__ encW0,   const float* __restrict__ decW0,
    float* __restrict__ P) {
    __shared__ float es[10][D_];
    __shared__ float part[4][64][10];
    int by = blockIdx.y;
    bool enc = (by < 10);
    int r0 = enc ? by * 10 : 100 + (by - 10) * 10;
    int s0 = enc ? by * 10 : (by - 10) * 10;
    const float* emb = enc ? enc_emb : dec_emb;
    const float* W   = enc ? encW0 : decW0;
    int tid = threadIdx.x;
    #pragma unroll
    for (int it = 0; it < 5; ++it) {
        int i4 = it * 256 + tid;
        int rr = i4 >> 7, cc = i4 & 127;
        ((float4*)es[rr])[cc] = ((const float4*)(emb + (size_t)(s0 + rr) * D_))[cc];
    }
    __syncthreads();
    int o   = tid & 63;
    int seg = tid >> 6;
    int np = blockIdx.x * 64 + o;
    int n = (np & 3) * D_ + (np >> 2);
    const float* wr = W + (size_t)n * D_ + seg * 128;
    float acc[10];
    #pragma unroll
    for (int rr = 0; rr < 10; ++rr) acc[rr] = 0.f;
    for (int k = 0; k < 128; k += 4) {
        float4 w4 = *(const float4*)(wr + k);
        int kb = seg * 128 + k;
        #pragma unroll
        for (int rr = 0; rr < 10; ++rr)
            acc[rr] += es[rr][kb] * w4.x + es[rr][kb+1] * w4.y
                     + es[rr][kb+2] * w4.z + es[rr][kb+3] * w4.w;
    }
    #pragma unroll
    for (int rr = 0; rr < 10; ++rr) part[seg][o][rr] = acc[rr];
    __syncthreads();
    for (int i = tid; i < 640; i += 256) {
        int o2 = i & 63, rr = i >> 6;
        P[(size_t)(r0 + rr) * G_ + blockIdx.x * 64 + o2] =
            (part[0][o2][rr] + part[1][o2][rr]) + (part[2][o2][rr] + part[3][o2][rr]);
    }
}

// ---------------------------------------------------------------------------
// MFMA LSTM cell. R14: LDS-shared A.
// Block = 512 thr = 8 waves = 2 K-groups x (2 m-waves x 2 n-waves).
// BM=256, BN'=64; wave tile 128 x 32 (8 m-frags x 2 n'-frags, acc 64 VGPR).
//
// Rationale (R8/R9/R10 all ~56-61us, MfmaUtil ~25%): per-chunk wall
// ~8.6Kcy vs 931cy of MFMA -- bound on per-CU global/L2 operand service.
// Old layout: 4 m-waves/group with disjoint rows -> A (128KB/block-phase)
// unshareable. New layout: the 2 n-waves of a (group, m-half) read the
// SAME 128 rows -> A staged once per group per chunk into an LDS ring
// (2 x 32KB per group) via global_load_lds and read twice from LDS.
// Global demand/block-phase: 256KB -> 96KB (A-stage 64 + B-regs 32);
// LDS (separate port) carries 128KB reads + 64KB writes.
// LDS total 131072 (dynamic opt-in); epilogue gf[256][68] aliases it.
// 1 block/CU; per-phase __syncthreads auto-drains the early-issued
// stages (~2000cy of cover). Same grid shape and 2D XCD decode as R1.
// ---------------------------------------------------------------------------
struct CellJob {
    const _Float16 *a0h, *a0l, *w0h, *w0l;
    int kclo0, kchi0;
    const _Float16 *a1h, *a1l, *w1h, *w1l;
    int kclo1, kchi1;
    const float *biasP;
    const float *P;          // permuted input-projection rows, or nullptr
    const int  *idx;
    int idx_stride, emb_rows;
    float *c_io;
    _Float16 *hh_out, *hl_out;
};

__global__ void __launch_bounds__(512, 2) lstm_cell_mfma(CellJob J0, CellJob J1) {
    extern __shared__ char smem[];            // 131072 B
    float (*gf)[68] = (float (*)[68])smem;    // epilogue alias (69632 B)

    const CellJob J = (blockIdx.z == 0) ? J0 : J1;

    const int tid  = threadIdx.x;
    const int w    = tid >> 6;
    const int lane = tid & 63;
    const int g    = w >> 2;        // K-group
    const int v    = w & 3;         // wave within group
    const int mw   = v >> 1;        // m-half (128 rows)
    const int nw   = v & 1;         // n-half (32 n')
    const int id   = blockIdx.x;    // 0..255
    const int xcd  = id & 7;
    const int rest = id >> 3;
    const int mt   = ((rest & 3) << 1) | (xcd >> 2);   // m-tile 0..7
    const int bx   = ((rest >> 2) << 2) | (xcd & 3);   // n'-tile 0..31
    const int m0   = mt * 256;

    const _Float16* Ah = g ? J.a1h : J.a0h;
    const _Float16* Al = g ? J.a1l : J.a0l;
    const _Float16* Wh = g ? J.w1h : J.w0h;
    const _Float16* Wl = g ? J.w1l : J.w0l;
    const int kclo = g ? J.kclo1 : J.kclo0;
    const int kchi = g ? J.kchi1 : J.kchi0;

    const int wfr = bx * 4 + nw * 2;          // wave's 2 B n'-frags

    f32x4 acc[8][2];
    #pragma unroll
    for (int f = 0; f < 8; ++f) {
        acc[f][0] = f32x4{0.f, 0.f, 0.f, 0.f};
        acc[f][1] = f32x4{0.f, 0.f, 0.f, 0.f};
    }

    char* const gbase = smem + (g << 16);     // 64 KB per group

    // Stage A-chunk (256 rows x 32 K, hi/lo = 32 tiles of 1 KB) for this
    // group: wave v stages tiles v*8..v*8+7 (frags v*4..v*4+3, both planes).
    auto stageA = [&](int buf, int kc) {
        char* d = gbase + buf * 32768 + (v << 13);   // v*8 KB
        #pragma unroll
        for (int s = 0; s < 8; ++s) {
            const int t    = v * 8 + s;
            const int fIdx = t >> 1;                 // A row-frag 0..15
            const _Float16* sp = ((t & 1) ? Al : Ah)
                + (((size_t)((m0 >> 4) + fIdx) * 16 + kc) << 9) + (size_t)lane * 8;
            glds16(sp, d + s * 1024);
        }
    };
    // B: wave-private, 2 n'-frags hi/lo from global (registers).
    auto ldB = [&](half8* Bv, int kc) {
        #pragma unroll
        for (int jj = 0; jj < 2; ++jj) {
            size_t off = (((size_t)(wfr + jj) * 16 + kc) << 9) + (size_t)lane * 8;
            Bv[jj * 2]     = *(const half8*)(Wh + off);
            Bv[jj * 2 + 1] = *(const half8*)(Wl + off);
        }
    };
    auto compute = [&](const half8* Bv, int buf) {
        const char* r = gbase + buf * 32768 + (mw << 14) + lane * 16;  // mw*16KB
        half8 Ar[16];
        #pragma unroll
        for (int t = 0; t < 16; ++t)
            Ar[t] = *(const half8*)(r + t * 1024);
        #pragma unroll
        for (int jj = 0; jj < 2; ++jj) {
            #pragma unroll
            for (int f = 0; f < 8; ++f) {
                acc[f][jj] = MFMA16(Ar[2*f],     Bv[jj*2],     acc[f][jj]);
                acc[f][jj] = MFMA16(Ar[2*f],     Bv[jj*2 + 1], acc[f][jj]);
                acc[f][jj] = MFMA16(Ar[2*f + 1], Bv[jj*2],     acc[f][jj]);
            }
        }
    };

    half8 B0[4], B1[4];
    const int P = kchi - kclo;    // 8 or 16, equal across both groups

    // Prologue
    stageA(0, kclo);
    ldB(B0, kclo);
    __syncthreads();              // drains vmcnt -> buf0 + B0 ready

    // Phases in pairs (P is even). Phase u: stage buf (u+1)&1 with chunk
    // kc+1 + prefetch B, then compute chunk kc from buf u&1. The phase-end
    // __syncthreads (vmcnt0+lgkmcnt0 drain) publishes the stage.
    for (int u = 0; u < P; u += 2) {
        {   // even phase: compute buf0/B0, stage buf1/B1
            const int kc = kclo + u;
            stageA(1, kc + 1);
            ldB(B1, kc + 1);
            __builtin_amdgcn_sched_barrier(0);
            compute(B0, 0);
            __syncthreads();
        }
        {   // odd phase: compute buf1/B1, stage buf0/B0 (if more)
            const int kc = kclo + u + 1;
            if (u + 2 < P) {
                stageA(0, kc + 1);
                ldB(B0, kc + 1);
            }
            __builtin_amdgcn_sched_barrier(0);
            compute(B1, 1);
            __syncthreads();
        }
    }

    // ---- epilogue: 256 m-rows; group-0 writes, group-1 adds ----
    const int rbase = (lane >> 4) << 2;
    const int cbase = lane & 15;
    if (g == 0) {
        #pragma unroll
        for (int f = 0; f < 8; ++f)
            #pragma unroll
            for (int jj = 0; jj < 2; ++jj) {
                int nc = nw * 32 + jj * 16 + cbase;
                #pragma unroll
                for (int r = 0; r < 4; ++r)
                    gf[mw * 128 + f * 16 + rbase + r][nc] = acc[f][jj][r];
            }
    }
    __syncthreads();
    if (g == 1) {
        #pragma unroll
        for (int f = 0; f < 8; ++f)
            #pragma unroll
            for (int jj = 0; jj < 2; ++jj) {
                int nc = nw * 32 + jj * 16 + cbase;
                #pragma unroll
                for (int r = 0; r < 4; ++r)
                    gf[mw * 128 + f * 16 + rbase + r][nc] += acc[f][jj][r];
            }
    }
    __syncthreads();
    {
        const int mr = tid >> 1;            // 0..255
        const int q  = tid & 1;             // d-octet half
        const int mg = m0 + mr;
        const float4* brow = (const float4*)(J.biasP + (bx << 6));
        const float4* Pr = nullptr;
        if (J.P) {
            int s = J.idx[mg * J.idx_stride];
            s = min(max(s, 0), J.emb_rows - 1);
            Pr = (const float4*)(J.P + (size_t)s * G_ + (bx << 6));
        }
        float* crow = J.c_io + (size_t)mg * D_ + (bx << 4) + (q << 3);
        float4 cv0 = ((float4*)crow)[0];
        float4 cv1 = ((float4*)crow)[1];
        _Float16 hh8[8], hl8[8];
        #pragma unroll
        for (int e = 0; e < 8; ++e) {
            const int dl = (q << 3) + e;
            float4 g4 = *(float4*)&gf[mr][dl << 2];
            float4 b4 = brow[dl];
            float gi = g4.x + b4.x, gF = g4.y + b4.y;
            float gg = g4.z + b4.z, go = g4.w + b4.w;
            if (Pr) {
                float4 p4 = Pr[dl];
                gi += p4.x; gF += p4.y; gg += p4.z; go += p4.w;
            }
            float cc = (e < 4) ? (&cv0.x)[e] : (&cv1.x)[e - 4];
            float cn = sigm(gF) * cc + sigm(gi) * tanhf(gg);
            float hn = sigm(go) * tanhf(cn);
            if (e < 4) (&cv0.x)[e] = cn; else (&cv1.x)[e - 4] = cn;
            _Float16 hH = (_Float16)hn;
            hh8[e] = hH;
            hl8[e] = (_Float16)(hn - (float)hH);
        }
        ((float4*)crow)[0] = cv0;
        ((float4*)crow)[1] = cv1;
        const int kk0 = (bx << 4) + (q << 3);          // 8-aligned
        size_t hbase = ((size_t)((mg >> 4) * 16 + (kk0 >> 5)) << 9)
                     + (size_t)((mg & 15) | (((kk0 >> 3) & 3) << 4)) * 8;
        *(half8*)(J.hh_out + hbase) = *(half8*)hh8;
        *(half8*)(J.hl_out + hbase) = *(half8*)hl8;
    }
}

// ---------------------------------------------------------------------------
// MFMA logits + argmax. 128 blocks x 1 wave; each wave owns 16 rows and
// the FULL K=512 (no cross-wave reduction, no partials).
// ---------------------------------------------------------------------------
__global__ __launch_bounds__(64) void logits_mfma(
    const _Float16* __restrict__ Ah, const _Float16* __restrict__ Al,
    const _Float16* __restrict__ Bh, const _Float16* __restrict__ Bl,
    const float* __restrict__ postb, float* __restrict__ out,
    int t, int* __restrict__ pred) {
    __shared__ float gf2[16][85];
    __shared__ float pb[VT_];
    const int lane = threadIdx.x;
    const int m0  = blockIdx.x * 16;
    const int afr = blockIdx.x;

    f32x4 acc[5];
    #pragma unroll
    for (int j = 0; j < 5; ++j) acc[j] = f32x4{0.f, 0.f, 0.f, 0.f};

    size_t lo8 = (size_t)lane * 8;
    for (int kc = 0; kc < 16; ++kc) {
        half8 Ahh, All, Bh8[5], Bl8[5];
        {
            size_t off = (((size_t)afr * 16 + kc) << 9) + lo8;
            Ahh = *(const half8*)(Ah + off);
            All = *(const half8*)(Al + off);
        }
        #pragma unroll
        for (int j = 0; j < 5; ++j) {
            size_t off = (((size_t)(j * 16 + kc)) << 9) + lo8;
            Bh8[j] = *(const half8*)(Bh + off);
            Bl8[j] = *(const half8*)(Bl + off);
        }
        #pragma unroll
        for (int j = 0; j < 5; ++j) {
            acc[j] = MFMA16(Ahh, Bh8[j], acc[j]);
            acc[j] = MFMA16(Ahh, Bl8[j], acc[j]);
            acc[j] = MFMA16(All, Bh8[j], acc[j]);
        }
    }

    if (lane < 40) ((float2*)pb)[lane] = ((const float2*)postb)[lane];
    const int quad = lane >> 4, c = lane & 15;
    #pragma unroll
    for (int j = 0; j < 5; ++j)
        #pragma unroll
        for (int r = 0; r < 4; ++r)
            gf2[quad * 4 + r][j * 16 + c] = acc[j][r];
    __syncthreads();
    if (lane < 16) {
        int r = lane;
        float best = -3.4e38f; int bi = 0;
        #pragma unroll
        for (int v = 0; v < VT_; ++v) {
            float x = gf2[r][v] + pb[v];
            if (x > best) { best = x; bi = v; }
        }
        pred[m0 + r] = bi;
        float* orow = out + (size_t)(m0 + r) * (T_ * VT_) + (size_t)t * VT_;
        #pragma unroll
        for (int v4 = 0; v4 < VT_ / 4; ++v4) {
            float4 g4 = *(float4*)&gf2[r][v4 * 4];
            float4 b4 = *(float4*)&pb[v4 * 4];
            float4 o4 = {g4.x + b4.x, g4.y + b4.y, g4.z + b4.z, g4.w + b4.w};
            *(float4*)(orow + v4 * 4) = o4;
        }
    }
}

// ---------------------------------------------------------------------------
extern "C" void kernel_launch(void* const* d_in, const int* in_sizes, int n_in,
                              void* d_out, int out_size, void* d_ws, size_t ws_size,
                              hipStream_t stream) {
    (void)in_sizes; (void)n_in; (void)out_size; (void)ws_size;

    const int*   src     = (const int*)d_in[0];
    const int*   tgt     = (const int*)d_in[1];
    const float* enc_emb = (const float*)d_in[2];
    const float* dec_emb = (const float*)d_in[3];
    const float* enc_Wih = (const float*)d_in[4];
    const float* enc_Whh = (const float*)d_in[5];
    const float* enc_bih = (const float*)d_in[6];
    const float* enc_bhh = (const float*)d_in[7];
    const float* dec_Wih = (const float*)d_in[8];
    const float* dec_Whh = (const float*)d_in[9];
    const float* dec_bih = (const float*)d_in[10];
    const float* dec_bhh = (const float*)d_in[11];
    const float* post_W  = (const float*)d_in[12];
    const float* post_b  = (const float*)d_in[13];

    // ---- ws layout (~50 MiB) ----
    char* wsb = (char*)d_ws;
    int*   pred  = (int*)wsb;                                   // 16 KB
    float* biasB = (float*)(wsb + 16384);                       // 32 KB
    float* Ptab  = (float*)(wsb + 16384 + 32768);               // 1.41 MiB
    char*  zbase = wsb + 16384 + 32768 + 180 * G_ * 4;          // zero-span
    float* C0 = (float*)zbase;
    float* C1 = C0 + BD;
    _Float16* Hh00 = (_Float16*)(C1 + BD);
    _Float16* Hh10 = Hh00 + BD;
    _Float16* Hl00 = Hh10 + BD;
    _Float16* Hl10 = Hl00 + BD;
    _Float16* Hh01 = Hl10 + BD;   // not zeroed (fully written before read)
    _Float16* Hh11 = Hh01 + BD;
    _Float16* Hl01 = Hh11 + BD;
    _Float16* Hl11 = Hl01 + BD;
    _Float16* Wb   = Hl11 + BD;                      // 6 split matrices, 24 MiB
    _Float16* PwH  = Wb + 6 * 2 * LWE;               // post_W hi frag tiles
    _Float16* PwL  = PwH + (size_t)VT_ * D_;         // post_W lo frag tiles

    _Float16* Hhi[2][2] = { { Hh00, Hh01 }, { Hh10, Hh11 } };
    _Float16* Hlo[2][2] = { { Hl00, Hl01 }, { Hl10, Hl11 } };
    float*    Cp[2]     = { C0, C1 };
    auto WP = [&](int m, int pl) { return Wb + (size_t)m * (2 * LWE) + (size_t)pl * LWE; };

    float* out = (float*)d_out;

    // ---- precompute ----
    zero_ws<<<4096, 256, 0, stream>>>((int4*)zbase, (16 * 1024 * 1024) / 16);
    init_pred<<<8, 256, 0, stream>>>(tgt, pred);
    split_weights<<<3072, 256, 0, stream>>>(
        enc_Whh, enc_Wih + LWE, enc_Whh + LWE,
        dec_Whh, dec_Wih + LWE, dec_Whh + LWE, Wb);
    split_postW<<<20, 256, 0, stream>>>(post_W, PwH, PwL);
    perm_bias<<<32, 256, 0, stream>>>(enc_bih, enc_bhh, dec_bih, dec_bhh, biasB);
    {
        dim3 gP(32, 18);
        compute_P<<<gP, 256, 0, stream>>>(enc_emb, dec_emb, enc_Wih, dec_Wih, Ptab);
    }

    // ---- dynamic LDS opt-in (one-time) ----
    static int s_attr = 0;
    if (!s_attr) {
        hipFuncSetAttribute((const void*)lstm_cell_mfma,
                            hipFuncAttributeMaxDynamicSharedMemorySize, 131072);
        s_attr = 1;
    }

    dim3 grid1(256, 1, 1);    // single job
    dim3 grid2(256, 1, 2);    // paired jobs
    int c0 = 0, c1 = 0;

    auto mkL0 = [&](bool enc, const int* ix, int stride, int rows) {
        int m = enc ? 0 : 3;
        CellJob j;
        j.a0h = Hhi[0][c0]; j.a0l = Hlo[0][c0];
        j.w0h = WP(m, 0);   j.w0l = WP(m, 1);
        j.kclo0 = 0; j.kchi0 = 8;
        j.a1h = Hhi[0][c0]; j.a1l = Hlo[0][c0];
        j.w1h = WP(m, 0);   j.w1l = WP(m, 1);
        j.kclo1 = 8; j.kchi1 = 16;
        j.biasP = biasB + (enc ? 0 : 2) * G_;
        j.P = enc ? Ptab : Ptab + (size_t)100 * G_;
        j.idx = ix; j.idx_stride = stride; j.emb_rows = rows;
        j.c_io = Cp[0];
        j.hh_out = Hhi[0][c0 ^ 1]; j.hl_out = Hlo[0][c0 ^ 1];
        return j;
    };
    auto mkL1 = [&](bool enc) {
        int mi = enc ? 1 : 4, mh = enc ? 2 : 5;
        CellJob j;
        j.a0h = Hhi[0][c0]; j.a0l = Hlo[0][c0];
        j.w0h = WP(mi, 0);  j.w0l = WP(mi, 1);
        j.kclo0 = 0; j.kchi0 = 16;
        j.a1h = Hhi[1][c1]; j.a1l = Hlo[1][c1];
        j.w1h = WP(mh, 0);  j.w1l = WP(mh, 1);
        j.kclo1 = 0; j.kchi1 = 16;
        j.biasP = biasB + (enc ? 1 : 3) * G_;
        j.P = nullptr; j.idx = nullptr; j.idx_stride = 0; j.emb_rows = 0;
        j.c_io = Cp[1];
        j.hh_out = Hhi[1][c1 ^ 1]; j.hl_out = Hlo[1][c1 ^ 1];
        return j;
    };

    // -------- encoder (layer1(t) paired with layer0(t+1)) --------
    {
        CellJob j0 = mkL0(true, src + 0, T_, 100);
        lstm_cell_mfma<<<grid1, 512, 131072, stream>>>(j0, j0);
        c0 ^= 1;
        for (int t = 0; t < T_ - 1; ++t) {
            CellJob jA = mkL1(true);                       // layer1(t)
            CellJob jB = mkL0(true, src + t + 1, T_, 100); // layer0(t+1)
            lstm_cell_mfma<<<grid2, 512, 131072, stream>>>(jA, jB);
            c1 ^= 1; c0 ^= 1;
        }
        CellJob jZ = mkL1(true);
        lstm_cell_mfma<<<grid1, 512, 131072, stream>>>(jZ, jZ);
        c1 ^= 1;
    }

    // -------- decoder (greedy feedback, serial) --------
    for (int t = 0; t < T_; ++t) {
        CellJob j0 = mkL0(false, pred, 1, VT_);
        lstm_cell_mfma<<<grid1, 512, 131072, stream>>>(j0, j0);
        c0 ^= 1;
        CellJob j1 = mkL1(false);
        lstm_cell_mfma<<<grid1, 512, 131072, stream>>>(j1, j1);
        c1 ^= 1;
        logits_mfma<<<128, 64, 0, stream>>>(
            Hhi[1][c1], Hlo[1][c1], PwH, PwL, post_b, out, t, pred);
    }
}